// Round 1
// baseline (287.415 us; speedup 1.0000x reference)
//
#include <hip/hip_runtime.h>
#include <hip/hip_bf16.h>
#include <stdint.h>

typedef __attribute__((ext_vector_type(8))) short bf16x8;
typedef __attribute__((ext_vector_type(4))) float f32x4;

__device__ __forceinline__ unsigned short f2bf(float f) {
  unsigned int u = __float_as_uint(f);
  u = u + 0x7fffu + ((u >> 16) & 1u);   // RNE
  return (unsigned short)(u >> 16);
}

// ---------------- prep kernels ----------------
// s[b][c] = lin_scale * dot(style[b], mod_weight[c]) + mod_bias[c]
__global__ void k_style(const float* __restrict__ style, const float* __restrict__ mw,
                        const float* __restrict__ mb, float* __restrict__ s) {
  __shared__ float st[512];
  const int b = blockIdx.x, t = threadIdx.x;
  st[t]       = style[b*512 + t];
  st[t + 256] = style[b*512 + t + 256];
  __syncthreads();
  for (int k = 0; k < 2; ++k) {
    int c = t + k*256;
    const float* row = mw + (size_t)c * 512;
    float acc = 0.f;
    for (int j = 0; j < 512; ++j) acc += st[j] * row[j];
    s[b*512 + c] = acc * 0.04419417382415922f + mb[c];  // 1/sqrt(512)
  }
}

// wsq[o][ci] = sum_k w[0][o][ci][k]^2
__global__ void k_wsq(const float* __restrict__ w, float* __restrict__ wsq) {
  int g = blockIdx.x * 256 + threadIdx.x;     // o*512+ci
  const float* p = w + (size_t)g * 9;
  float acc = 0.f;
  #pragma unroll
  for (int t = 0; t < 9; ++t) { float v = p[t]; acc += v*v; }
  wsq[g] = acc;
}

// demod[b][o] = rsqrt(cs^2 * sum_ci s[b][ci]^2 * wsq[o][ci] + 1e-8)
__global__ void k_demod(const float* __restrict__ s, const float* __restrict__ wsq,
                        float* __restrict__ dm) {
  __shared__ float s2[512];
  const int g = blockIdx.x * 256 + threadIdx.x;
  const int b = g >> 9, o = g & 511, t = threadIdx.x;
  float v0 = s[b*512 + t], v1 = s[b*512 + t + 256];
  s2[t] = v0*v0; s2[t+256] = v1*v1;
  __syncthreads();
  const float* row = wsq + (size_t)o * 512;
  float acc = 0.f;
  for (int j = 0; j < 512; ++j) acc += s2[j] * row[j];
  dm[g] = rsqrtf(acc * (1.0f/4608.0f) + 1e-8f);
}

// wp[b][kk][cb][o][64ci] bf16, byte-in-row XOR-swizzled with ((o&7)<<4) so that a
// LINEAR global_load_lds of a 128x128B tile yields the swizzled LDS layout.
__global__ void k_wprep(const float* __restrict__ w, const float* __restrict__ s,
                        const float* __restrict__ dm, unsigned short* __restrict__ wp) {
  const int g = blockIdx.x * 256 + threadIdx.x;    // b*512*512 + o*512 + ci
  const int ci = g & 511, o = (g >> 9) & 511, b = g >> 18;
  const float m = 0.014731391274719739f /*1/sqrt(4608)*/ * s[b*512 + ci] * dm[b*512 + o];
  const float* w9 = w + ((size_t)o*512 + ci) * 9;
  const int cb = ci >> 6, cin = ci & 63;
  char* base = (char*)wp;
  const unsigned sw = (unsigned)(cin*2) ^ (unsigned)((o & 7) << 4);
  #pragma unroll
  for (int kk = 0; kk < 9; ++kk) {
    unsigned short h = f2bf(w9[kk] * m);
    size_t off = ((((size_t)b*9 + kk)*8 + cb)*512 + o) * 128 + sw;
    *(unsigned short*)(base + off) = h;
  }
}

// ---------------- conv kernel ----------------
// grid (32 pixel-tiles, 4 o-tiles, 8 batch), block 256 = 4 waves (2x2), wave tile 64x64.
// LDS A: 2 x [128 o][128B swizzled 64ci]  (double-buffered per (cb,kk))
// LDS B: [4 rows][64 cols][128B swizzled 64ci]  (single-buffered per cb, reused by 9 taps)
__global__ __launch_bounds__(256, 2) void k_conv(const float* __restrict__ in,
                                                 const unsigned short* __restrict__ wp,
                                                 float* __restrict__ out) {
  __shared__ __align__(16) unsigned char ldsA[32768];
  __shared__ __align__(16) unsigned char ldsB[32768];

  const int tid = threadIdx.x;
  const int lan15 = tid & 15;
  const int lgrp = (tid >> 4) & 3;
  const int wid = tid >> 6;
  const int wm = wid >> 1, wn = wid & 1;
  const int pt = blockIdx.x, ot = blockIdx.y, b = blockIdx.z;
  const int o0 = ot * 128, y0 = pt * 2;

  const float* inb = in + (size_t)b * 512 * 4096;
  const unsigned short* wpb = wp + (size_t)b * 9 * 8 * 512 * 64;

  auto stageA = [&](int kk, int cb, int par) {
    const char* src = (const char*)(wpb + (((size_t)kk*8 + cb)*512 + (size_t)o0) * 64);
    unsigned char* dst = ldsA + (par << 14);
    #pragma unroll
    for (int r = 0; r < 4; ++r) {
      __builtin_amdgcn_global_load_lds(
        (const __attribute__((address_space(1))) unsigned int*)(src + tid*16 + r*4096),
        (__attribute__((address_space(3))) unsigned int*)(dst + tid*16 + r*4096),
        16, 0, 0);
    }
  };

  auto stageB = [&](int cb) {
    const int lx = tid & 15;
    const int hi = tid >> 4;
    #pragma unroll
    for (int rnd = 0; rnd < 8; ++rnd) {
      const int combo = hi + rnd*16;   // 0..127
      const int cp = combo & 31;       // ci pair index
      const int ir = combo >> 5;       // 0..3  (input row y0-1+ir)
      const int yi = y0 - 1 + ir;
      if (yi >= 0 && yi < 64) {
        const float* p0 = inb + ((size_t)(cb*64 + cp*2) * 64 + yi) * 64;
        #pragma unroll
        for (int e = 0; e < 4; ++e) {
          const int x = lx + e*16;
          float a = p0[x];
          float c = p0[x + 4096];          // next ci plane
          unsigned int pk = (unsigned)f2bf(a) | ((unsigned)f2bf(c) << 16);
          const int pix = ir*64 + x;
          *(unsigned int*)(ldsB + pix*128 + ((cp*4) ^ ((pix & 7) << 4))) = pk;
        }
      }
    }
  };

  // zero B (covers vertical-halo rows forever; interior rewritten each cb)
  #pragma unroll
  for (int i = 0; i < 32; ++i) ((unsigned int*)ldsB)[tid + i*256] = 0u;
  __syncthreads();
  stageB(0);
  stageA(0, 0, 0);

  f32x4 acc[4][4];
  #pragma unroll
  for (int mf = 0; mf < 4; ++mf)
    #pragma unroll
    for (int nf = 0; nf < 4; ++nf)
      acc[mf][nf] = (f32x4){0.f, 0.f, 0.f, 0.f};

  int aOff[4];
  #pragma unroll
  for (int mf = 0; mf < 4; ++mf) {
    int o_rel = wm*64 + mf*16 + lan15;
    aOff[mf] = o_rel*128 + ((lgrp*16) ^ ((o_rel & 7) << 4));
  }
  int cOff[3][4];
  #pragma unroll
  for (int kx = 0; kx < 3; ++kx)
    #pragma unroll
    for (int nf = 0; nf < 4; ++nf) {
      int x = nf*16 + lan15 + kx - 1;
      int ic = x < 0 ? 0 : (x > 63 ? 63 : x);   // clamped; edge lanes zeroed at use
      cOff[kx][nf] = ic*128 + ((lgrp*16) ^ ((ic & 7) << 4));
    }
  const bool zL = (lan15 == 0), zR = (lan15 == 15);

  for (int cb = 0; cb < 8; ++cb) {
    #pragma unroll
    for (int kk = 0; kk < 9; ++kk) {
      const int gg = cb*9 + kk;
      __syncthreads();               // publishes A(gg) [vmcnt drain] and B(cb)
      if (gg < 71) {
        const int nkk = (kk == 8) ? 0 : kk + 1;
        const int ncb = (kk == 8) ? cb + 1 : cb;
        stageA(nkk, ncb, (gg + 1) & 1);
      }
      const int ky = kk / 3, kx = kk % 3;
      const unsigned char* Ab = ldsA + ((gg & 1) << 14);
      const unsigned char* Bb = ldsB + ((wn + ky) << 13);  // input row = wn + ky
      #pragma unroll
      for (int ks = 0; ks < 2; ++ks) {
        bf16x8 af[4], bfr[4];
        #pragma unroll
        for (int mf = 0; mf < 4; ++mf)
          af[mf] = *(const bf16x8*)(Ab + (aOff[mf] ^ (ks << 6)));
        #pragma unroll
        for (int nf = 0; nf < 4; ++nf) {
          bf16x8 v = *(const bf16x8*)(Bb + (cOff[kx][nf] ^ (ks << 6)));
          if (kx == 0 && nf == 0) { if (zL) v = bf16x8{0,0,0,0,0,0,0,0}; }
          if (kx == 2 && nf == 3) { if (zR) v = bf16x8{0,0,0,0,0,0,0,0}; }
          bfr[nf] = v;
        }
        #pragma unroll
        for (int mf = 0; mf < 4; ++mf)
          #pragma unroll
          for (int nf = 0; nf < 4; ++nf)
            acc[mf][nf] = __builtin_amdgcn_mfma_f32_16x16x32_bf16(af[mf], bfr[nf], acc[mf][nf], 0, 0, 0);
      }
      if (kk == 8 && cb < 7) {
        __syncthreads();             // all waves done reading B(cb)
        stageB(cb + 1);
      }
    }
  }

  float* outb = out + (size_t)b * 512 * 4096;
  #pragma unroll
  for (int mf = 0; mf < 4; ++mf) {
    const int o = o0 + wm*64 + mf*16 + lgrp*4;
    #pragma unroll
    for (int nf = 0; nf < 4; ++nf) {
      const int p = pt*128 + wn*64 + nf*16 + lan15;
      #pragma unroll
      for (int r = 0; r < 4; ++r)
        outb[(size_t)(o + r) * 4096 + p] = acc[mf][nf][r];
    }
  }
}

extern "C" void kernel_launch(void* const* d_in, const int* in_sizes, int n_in,
                              void* d_out, int out_size, void* d_ws, size_t ws_size,
                              hipStream_t stream) {
  const float* input  = (const float*)d_in[0];
  const float* style  = (const float*)d_in[1];
  const float* weight = (const float*)d_in[2];
  const float* mw     = (const float*)d_in[3];
  const float* mb     = (const float*)d_in[4];
  float* out = (float*)d_out;
  char* ws = (char*)d_ws;
  float* s     = (float*)ws;                       // 16 KB
  float* demod = (float*)(ws + 16384);             // 16 KB
  float* wsq   = (float*)(ws + 32768);             // 1 MB
  unsigned short* wp = (unsigned short*)(ws + 32768 + 1048576);  // 36 MB

  hipLaunchKernelGGL(k_style, dim3(8),    dim3(256), 0, stream, style, mw, mb, s);
  hipLaunchKernelGGL(k_wsq,   dim3(1024), dim3(256), 0, stream, weight, wsq);
  hipLaunchKernelGGL(k_demod, dim3(16),   dim3(256), 0, stream, s, wsq, demod);
  hipLaunchKernelGGL(k_wprep, dim3(8192), dim3(256), 0, stream, weight, s, demod, wp);
  hipLaunchKernelGGL(k_conv,  dim3(32, 4, 8), dim3(256), 0, stream, input, wp, out);
}